// Round 3
// baseline (168.822 us; speedup 1.0000x reference)
//
#include <hip/hip_runtime.h>
#include <cstdint>

#define DIMD 1024
#define NROWS 8192
#define KDIM 2048   // 2*DIM

typedef unsigned short u16;
typedef __bf16 bf16x8 __attribute__((ext_vector_type(8)));
typedef float f32x4 __attribute__((ext_vector_type(4)));

__device__ __forceinline__ u16 f2bf(float f) {
  unsigned u = __builtin_bit_cast(unsigned, f);
  return (u16)((u + 0x7FFFu + ((u >> 16) & 1u)) >> 16);  // RNE
}

// Branch-free exact-enough GELU (A&S 7.1.26 erf, |err| <= 1.5e-7).
__device__ __forceinline__ float gelu_exact(float x) {
  float s = 0.70710678118654752f * x;
  float a = fabsf(s);
  float k = __fdividef(1.0f, fmaf(0.3275911f, a, 1.0f));
  float p = 1.061405429f;
  p = fmaf(p, k, -1.453152027f);
  p = fmaf(p, k, 1.421413741f);
  p = fmaf(p, k, -0.284496736f);
  p = fmaf(p, k, 0.254829592f);
  p = p * k;
  float e = __expf(-s * s);
  float erf_s = copysignf(fmaf(-p, e, 1.0f), s);
  return 0.5f * x * (1.0f + erf_s);
}

// ---------------------------------------------------------------------------
// Fused pre-kernel: conv(3x5)+bias+gelu -> x2 bf16, and w2 fp32->bf16 cast.
// (unchanged)
// ---------------------------------------------------------------------------
__global__ __launch_bounds__(256) void pre_kernel(
    const float* __restrict__ ifeats, const float* __restrict__ tn,
    const float* __restrict__ ta, const float* __restrict__ cw,
    const float* __restrict__ cb, const float* __restrict__ w2,
    u16* __restrict__ x2, u16* __restrict__ w2b) {
  const int b = blockIdx.x;
  const int t = threadIdx.x;
  if (b < NROWS) {
    __shared__ float si[DIMD], sn[DIMD], sa[DIMD];
    ((float4*)si)[t] = ((const float4*)(ifeats + (size_t)b * DIMD))[t];
    ((float4*)sn)[t] = ((const float4*)tn)[t];
    ((float4*)sa)[t] = ((const float4*)ta)[t];
    __syncthreads();
    const int c = t >> 7;
    const int w0 = (t & 127) << 3;
    float cwn[5], cwa[5], cwi[5];
#pragma unroll
    for (int k = 0; k < 5; ++k) {
      cwn[k] = cw[c * 15 + k];
      cwa[k] = cw[c * 15 + 5 + k];
      cwi[k] = cw[c * 15 + 10 + k];
    }
    const float bias = cb[c];
    float wn[12], wa[12], wi[12];
#pragma unroll
    for (int j = 0; j < 12; ++j) {
      int wp = w0 - 2 + j;
      bool ok = (wp >= 0) && (wp < DIMD);
      wn[j] = ok ? sn[wp] : 0.f;
      wa[j] = ok ? sa[wp] : 0.f;
      wi[j] = ok ? si[wp] : 0.f;
    }
    union { u16 o[8]; uint4 u; } pk;
#pragma unroll
    for (int s = 0; s < 8; ++s) {
      float x = bias;
#pragma unroll
      for (int k = 0; k < 5; ++k) {
        x = fmaf(cwn[k], wn[s + k], x);
        x = fmaf(cwa[k], wa[s + k], x);
        x = fmaf(cwi[k], wi[s + k], x);
      }
      pk.o[s] = f2bf(gelu_exact(x));
    }
    *(uint4*)(x2 + (size_t)b * KDIM + c * DIMD + w0) = pk.u;
  } else {
    const int t2 = (b - NROWS) * 256 + t;
    const float4* p = (const float4*)(w2 + (size_t)t2 * 8);
    float4 a = p[0], bb = p[1];
    union { u16 o[8]; uint4 v; } pk;
    pk.o[0] = f2bf(a.x);  pk.o[1] = f2bf(a.y);  pk.o[2] = f2bf(a.z);  pk.o[3] = f2bf(a.w);
    pk.o[4] = f2bf(bb.x); pk.o[5] = f2bf(bb.y); pk.o[6] = f2bf(bb.z); pk.o[7] = f2bf(bb.w);
    *(uint4*)(w2b + (size_t)t2 * 8) = pk.v;
  }
}

// ---------------------------------------------------------------------------
// GEMM v5: r0's proven skeleton (512 thr, 8 waves, BK=64, 2-buffer, aged
// async prefetch, verified 0-conflict XOR swizzle) with 128x256 block tile,
// per-wave 64x64 (4x4 acc).
//   Theory: r0 was LDS-read-throughput-bound (per CU per phase: 192
//   ds_read_b128 ~= 2300 cyc vs 1835 cyc measured phase; MFMA pipe ~8%).
//   4x4 acc cuts fragment reads per MFMA 1.5x (12 -> 8 b128 per 16 MFMA).
//   Grid 256 blocks (64 M-tiles x 4 N-tiles) = 1 block/CU, 8 waves/CU; LDS
//   96 KB. Phases stay coarse (16 reads + 32 MFMA per wave between barriers)
//   -- unlike r1/r2's starved 4-wave micro-phases.
// ---------------------------------------------------------------------------
__device__ __forceinline__ void gl_lds16(const u16* g, u16* l) {
  __builtin_amdgcn_global_load_lds(
      (__attribute__((address_space(1))) void*)g,
      (__attribute__((address_space(3))) void*)l, 16, 0, 0);
}

#define BK 64  // u16 per row per stage

__global__ __launch_bounds__(512, 2) void gemm_bt(
    const u16* __restrict__ A,      // x2 bf16 [8192, 2048]
    const u16* __restrict__ B,      // w2 bf16 [1024, 2048]
    const float* __restrict__ ifeats,
    const float* __restrict__ b2,
    float* __restrict__ out) {
  constexpr int K = KDIM;
  __shared__ __align__(16) u16 sA[2][128 * BK];  // 16 KB per buf
  __shared__ __align__(16) u16 sB[2][256 * BK];  // 32 KB per buf; 96 KB total

  const int tid = threadIdx.x;
  const int wv = tid >> 6;         // wave 0..7
  const int lane = tid & 63;
  // XCD-aware swizzle: 256 blocks, xcd = id&7 owns 8 M-strips x 4 N-blocks.
  const int id = blockIdx.x;       // 0..255
  const int xcd = id & 7;
  const int s_ = id >> 3;          // 0..31
  const int i0 = (xcd * 8 + (s_ >> 2)) * 128;
  const int j0 = (s_ & 3) * 256;

  const int wm = (wv & 1) * 64;    // wave tile: 64 (M) x 64 (N)
  const int wn = (wv >> 1) * 64;   // 0,64,128,192
  const int quad = lane >> 4;
  const int r16 = lane & 15;
  const int sw = r16 & 7;

  // staging: A tile 128 rows (2 units/wave), B tile 256 rows (4 units/wave);
  // unit = 8 rows x 128 B = one gl_lds16. XOR chunk swizzle (verified 0
  // conflicts): LDS[row][c] holds global chunk c ^ (row&7).
  const int srow = lane >> 3;                 // 0..7
  const int schunk = (lane & 7) ^ srow;       // pre-swizzled 16B chunk
  const u16* gA[2];
  const u16* gB[4];
#pragma unroll
  for (int i = 0; i < 2; ++i)
    gA[i] = A + (size_t)(i0 + wv * 16 + i * 8 + srow) * K + schunk * 8;
#pragma unroll
  for (int i = 0; i < 4; ++i)
    gB[i] = B + (size_t)(j0 + wv * 32 + i * 8 + srow) * K + schunk * 8;

  const f32x4 vzero = {0.f, 0.f, 0.f, 0.f};
  f32x4 acc[4][4];
#pragma unroll
  for (int a = 0; a < 4; ++a)
#pragma unroll
    for (int b = 0; b < 4; ++b) acc[a][b] = vzero;

  auto stage = [&](int buf, int k0) {
#pragma unroll
    for (int i = 0; i < 2; ++i)
      gl_lds16(gA[i] + k0, &sA[buf][(wv * 16 + i * 8) * BK]);
#pragma unroll
    for (int i = 0; i < 4; ++i)
      gl_lds16(gB[i] + k0, &sB[buf][(wv * 32 + i * 8) * BK]);
  };

  auto compute = [&](int buf) {
#pragma unroll
    for (int s = 0; s < 2; ++s) {
      bf16x8 av[4], bv[4];
#pragma unroll
      for (int mt = 0; mt < 4; ++mt)
        av[mt] = *(const bf16x8*)&sA[buf][(wm + mt * 16 + r16) * BK + (((s * 4 + quad) ^ sw) << 3)];
#pragma unroll
      for (int nt = 0; nt < 4; ++nt)
        bv[nt] = *(const bf16x8*)&sB[buf][(wn + nt * 16 + r16) * BK + (((s * 4 + quad) ^ sw) << 3)];
#pragma unroll
      for (int mt = 0; mt < 4; ++mt)
#pragma unroll
        for (int nt = 0; nt < 4; ++nt)
          acc[mt][nt] = __builtin_amdgcn_mfma_f32_16x16x32_bf16(av[mt], bv[nt], acc[mt][nt], 0, 0, 0);
    }
  };

  stage(0, 0);
  for (int k0 = 0; k0 < K; k0 += 2 * BK) {
    __syncthreads();                    // drains buf0 loads; buf1 free
    if (k0 + BK < K) stage(1, k0 + BK); // async prefetch next stage
    compute(0);
    __syncthreads();                    // drains buf1 loads (aged one phase)
    if (k0 + 2 * BK < K) stage(0, k0 + 2 * BK);
    compute(1);
  }

  // epilogue: C/D layout col=lane&15, row=quad*4+reg
#pragma unroll
  for (int nt = 0; nt < 4; ++nt) {
    int col = j0 + wn + nt * 16 + r16;
    float bias = b2[col];
#pragma unroll
    for (int mt = 0; mt < 4; ++mt) {
      int rbase = i0 + wm + mt * 16 + quad * 4;
#pragma unroll
      for (int r = 0; r < 4; ++r) {
        size_t idx = (size_t)(rbase + r) * DIMD + col;
        out[idx] = ifeats[idx] + bias + acc[mt][nt][r];
      }
    }
  }
}

// ---------------------------------------------------------------------------
extern "C" void kernel_launch(void* const* d_in, const int* in_sizes, int n_in,
                              void* d_out, int out_size, void* d_ws, size_t ws_size,
                              hipStream_t stream) {
  const float* ifeats = (const float*)d_in[0];
  const float* tn     = (const float*)d_in[1];
  const float* ta     = (const float*)d_in[2];
  const float* cw     = (const float*)d_in[3];
  const float* cb     = (const float*)d_in[4];
  const float* w2     = (const float*)d_in[5];
  const float* b2     = (const float*)d_in[6];
  float* out = (float*)d_out;

  // ws: [0, 4MB) w2 bf16 | [4MB, 36MB) x2 bf16
  u16* w2b = (u16*)d_ws;
  u16* x2  = (u16*)((char*)d_ws + (size_t)DIMD * KDIM * 2);

  pre_kernel<<<NROWS + (DIMD * KDIM / 8) / 256, 256, 0, stream>>>(
      ifeats, tn, ta, cw, cb, w2, x2, w2b);
  gemm_bt<<<256, 512, 0, stream>>>(x2, w2b, ifeats, b2, out);
}

// Round 4
// 157.990 us; speedup vs baseline: 1.0686x; 1.0686x over previous
//
#include <hip/hip_runtime.h>
#include <cstdint>

#define DIMD 1024
#define NROWS 8192
#define KDIM 2048   // 2*DIM

typedef unsigned short u16;
typedef __bf16 bf16x8 __attribute__((ext_vector_type(8)));
typedef float f32x4 __attribute__((ext_vector_type(4)));

__device__ __forceinline__ u16 f2bf(float f) {
  unsigned u = __builtin_bit_cast(unsigned, f);
  return (u16)((u + 0x7FFFu + ((u >> 16) & 1u)) >> 16);  // RNE
}

// Branch-free exact-enough GELU (A&S 7.1.26 erf, |err| <= 1.5e-7).
__device__ __forceinline__ float gelu_exact(float x) {
  float s = 0.70710678118654752f * x;
  float a = fabsf(s);
  float k = __fdividef(1.0f, fmaf(0.3275911f, a, 1.0f));
  float p = 1.061405429f;
  p = fmaf(p, k, -1.453152027f);
  p = fmaf(p, k, 1.421413741f);
  p = fmaf(p, k, -0.284496736f);
  p = fmaf(p, k, 0.254829592f);
  p = p * k;
  float e = __expf(-s * s);
  float erf_s = copysignf(fmaf(-p, e, 1.0f), s);
  return 0.5f * x * (1.0f + erf_s);
}

// ---------------------------------------------------------------------------
// pre_kernel v2: conv(3x5)+bias+gelu -> x2 bf16, and w2 fp32->bf16 cast.
//   Changes vs v1 (theory: v1 recomputed the row-invariant tn/ta conv term
//   for every row and restaged tn/ta 8192x through LDS):
//   - 8 rows per block (grid 9216 -> 2048), no shared memory, no barriers.
//   - base[8] = bias + conv(tn) + conv(ta) precomputed ONCE per thread;
//     per-row work is only 5 FMA/output + gelu (3x less conv VALU).
//   - ifeats window [w0-2, w0+9] via 2 aligned float4 + 4 guarded edge
//     scalars (static register indexing, no scratch).
// ---------------------------------------------------------------------------
__global__ __launch_bounds__(256) void pre_kernel(
    const float* __restrict__ ifeats, const float* __restrict__ tn,
    const float* __restrict__ ta, const float* __restrict__ cw,
    const float* __restrict__ cb, const float* __restrict__ w2,
    u16* __restrict__ x2, u16* __restrict__ w2b) {
  const int b = blockIdx.x;
  const int t = threadIdx.x;
  if (b < 1024) {                  // 8 rows per block
    const int c = t >> 7;          // out channel 0/1
    const int w0 = (t & 127) << 3; // 8 outputs starting here
    float cwn[5], cwa[5], cwi[5];
#pragma unroll
    for (int k = 0; k < 5; ++k) {
      cwn[k] = cw[c * 15 + k];
      cwa[k] = cw[c * 15 + 5 + k];
      cwi[k] = cw[c * 15 + 10 + k];
    }
    const float bias = cb[c];
    // Row-invariant part: base[s] = bias + conv5(tn) + conv5(ta).
    float base[8];
    {
      float wn[12], wa[12];
#pragma unroll
      for (int j = 0; j < 12; ++j) {
        int wp = w0 - 2 + j;
        bool ok = (wp >= 0) && (wp < DIMD);
        wn[j] = ok ? tn[ok ? wp : 0] : 0.f;
        wa[j] = ok ? ta[ok ? wp : 0] : 0.f;
      }
#pragma unroll
      for (int s = 0; s < 8; ++s) {
        float x = bias;
#pragma unroll
        for (int k = 0; k < 5; ++k) {
          x = fmaf(cwn[k], wn[s + k], x);
          x = fmaf(cwa[k], wa[s + k], x);
        }
        base[s] = x;
      }
    }
    const bool has_l = (w0 > 0);
    const bool has_r = (w0 < DIMD - 8);
#pragma unroll 1
    for (int r = 0; r < 8; ++r) {
      const int row = b * 8 + r;
      const float* irow = ifeats + (size_t)row * DIMD;
      // window [w0-2, w0+9]: wi[0..1] left edge, wi[2..9] main, wi[10..11] right
      float wi[12];
      float4 m0 = *(const float4*)(irow + w0);
      float4 m1 = *(const float4*)(irow + w0 + 4);
      wi[0] = has_l ? irow[w0 - 2] : 0.f;
      wi[1] = has_l ? irow[w0 - 1] : 0.f;
      wi[2] = m0.x; wi[3] = m0.y; wi[4] = m0.z; wi[5] = m0.w;
      wi[6] = m1.x; wi[7] = m1.y; wi[8] = m1.z; wi[9] = m1.w;
      wi[10] = has_r ? irow[w0 + 8] : 0.f;
      wi[11] = has_r ? irow[w0 + 9] : 0.f;
      union { u16 o[8]; uint4 u; } pk;
#pragma unroll
      for (int s = 0; s < 8; ++s) {
        float x = base[s];
#pragma unroll
        for (int k = 0; k < 5; ++k) x = fmaf(cwi[k], wi[s + k], x);
        pk.o[s] = f2bf(gelu_exact(x));
      }
      *(uint4*)(x2 + (size_t)row * KDIM + c * DIMD + w0) = pk.u;
    }
  } else {
    const int t2 = (b - 1024) * 256 + t;   // 1024 blocks cover 1024x2048 w2
    const float4* p = (const float4*)(w2 + (size_t)t2 * 8);
    float4 a = p[0], bb = p[1];
    union { u16 o[8]; uint4 v; } pk;
    pk.o[0] = f2bf(a.x);  pk.o[1] = f2bf(a.y);  pk.o[2] = f2bf(a.z);  pk.o[3] = f2bf(a.w);
    pk.o[4] = f2bf(bb.x); pk.o[5] = f2bf(bb.y); pk.o[6] = f2bf(bb.z); pk.o[7] = f2bf(bb.w);
    *(uint4*)(w2b + (size_t)t2 * 8) = pk.v;
  }
}

// ---------------------------------------------------------------------------
// GEMM: verbatim r0 structure (the only measured-49us variant).
// 128x128 tile, 8 waves (512 thr) -> 16 waves/CU at 2 blocks/CU. BK=64
// double-buffered, async prefetch issued right after each barrier. XOR chunk
// swizzle -> 0 bank conflicts (verified). XCD swizzle: xcd=id&7 owns M-strip.
// ---------------------------------------------------------------------------
__device__ __forceinline__ void gl_lds16(const u16* g, u16* l) {
  __builtin_amdgcn_global_load_lds(
      (__attribute__((address_space(1))) void*)g,
      (__attribute__((address_space(3))) void*)l, 16, 0, 0);
}

#define BK 64  // u16 per row per stage

__global__ __launch_bounds__(512, 4) void gemm_bt(
    const u16* __restrict__ A,      // x2 bf16 [8192, 2048]
    const u16* __restrict__ B,      // w2 bf16 [1024, 2048]
    const float* __restrict__ ifeats,
    const float* __restrict__ b2,
    float* __restrict__ out) {
  constexpr int K = KDIM;
  __shared__ __align__(16) u16 sA[2][128 * BK];  // 16 KB per buf
  __shared__ __align__(16) u16 sB[2][128 * BK];

  const int tid = threadIdx.x;
  const int wv = tid >> 6;         // wave 0..7
  const int lane = tid & 63;
  // XCD-aware swizzle: linear id -> (i_blk, j_blk)
  const int id = blockIdx.x;       // 0..511
  const int xcd = id & 7;
  const int s_ = id >> 3;          // 0..63
  const int i0 = (xcd * 8 + (s_ >> 3)) * 128;
  const int j0 = (s_ & 7) * 128;

  const int wm = (wv & 1) * 64;    // wave tile: 64 (M) x 32 (N)
  const int wn = (wv >> 1) * 32;
  const int quad = lane >> 4;
  const int r16 = lane & 15;
  const int sw = r16 & 7;

  // staging: per wave 16 rows of A + 16 of B per stage; 8 rows per issue.
  const int srow = lane >> 3;                 // 0..7
  const int schunk = (lane & 7) ^ srow;       // XOR-swizzled 16B chunk
  const u16* gA[2];
  const u16* gB[2];
#pragma unroll
  for (int i = 0; i < 2; ++i) {
    int r = wv * 16 + i * 8 + srow;
    gA[i] = A + (size_t)(i0 + r) * K + schunk * 8;
    gB[i] = B + (size_t)(j0 + r) * K + schunk * 8;
  }

  const f32x4 vzero = {0.f, 0.f, 0.f, 0.f};
  f32x4 acc[4][2];
#pragma unroll
  for (int a = 0; a < 4; ++a)
#pragma unroll
    for (int b = 0; b < 2; ++b) acc[a][b] = vzero;

  auto stage = [&](int buf, int k0) {
#pragma unroll
    for (int i = 0; i < 2; ++i) {
      u16* la = &sA[buf][(wv * 16 + i * 8) * BK];
      u16* lb = &sB[buf][(wv * 16 + i * 8) * BK];
      gl_lds16(gA[i] + k0, la);
      gl_lds16(gB[i] + k0, lb);
    }
  };

  auto compute = [&](int buf) {
#pragma unroll
    for (int s = 0; s < 2; ++s) {
      bf16x8 av[4], bv[2];
#pragma unroll
      for (int mt = 0; mt < 4; ++mt)
        av[mt] = *(const bf16x8*)&sA[buf][(wm + mt * 16 + r16) * BK + (((s * 4 + quad) ^ sw) << 3)];
#pragma unroll
      for (int nt = 0; nt < 2; ++nt)
        bv[nt] = *(const bf16x8*)&sB[buf][(wn + nt * 16 + r16) * BK + (((s * 4 + quad) ^ sw) << 3)];
#pragma unroll
      for (int mt = 0; mt < 4; ++mt)
#pragma unroll
        for (int nt = 0; nt < 2; ++nt)
          acc[mt][nt] = __builtin_amdgcn_mfma_f32_16x16x32_bf16(av[mt], bv[nt], acc[mt][nt], 0, 0, 0);
    }
  };

  stage(0, 0);
  for (int k0 = 0; k0 < K; k0 += 2 * BK) {
    __syncthreads();                    // drains buf0 loads; buf1 free
    if (k0 + BK < K) stage(1, k0 + BK); // async prefetch next stage
    compute(0);
    __syncthreads();                    // drains buf1 loads (aged one phase)
    if (k0 + 2 * BK < K) stage(0, k0 + 2 * BK);
    compute(1);
  }

  // epilogue: C/D layout col=lane&15, row=quad*4+reg
#pragma unroll
  for (int nt = 0; nt < 2; ++nt) {
    int col = j0 + wn + nt * 16 + r16;
    float bias = b2[col];
#pragma unroll
    for (int mt = 0; mt < 4; ++mt) {
      int rbase = i0 + wm + mt * 16 + quad * 4;
#pragma unroll
      for (int r = 0; r < 4; ++r) {
        size_t idx = (size_t)(rbase + r) * DIMD + col;
        out[idx] = ifeats[idx] + bias + acc[mt][nt][r];
      }
    }
  }
}

// ---------------------------------------------------------------------------
extern "C" void kernel_launch(void* const* d_in, const int* in_sizes, int n_in,
                              void* d_out, int out_size, void* d_ws, size_t ws_size,
                              hipStream_t stream) {
  const float* ifeats = (const float*)d_in[0];
  const float* tn     = (const float*)d_in[1];
  const float* ta     = (const float*)d_in[2];
  const float* cw     = (const float*)d_in[3];
  const float* cb     = (const float*)d_in[4];
  const float* w2     = (const float*)d_in[5];
  const float* b2     = (const float*)d_in[6];
  float* out = (float*)d_out;

  // ws: [0, 4MB) w2 bf16 | [4MB, 36MB) x2 bf16
  u16* w2b = (u16*)d_ws;
  u16* x2  = (u16*)((char*)d_ws + (size_t)DIMD * KDIM * 2);

  pre_kernel<<<2048, 256, 0, stream>>>(ifeats, tn, ta, cw, cb, w2, x2, w2b);
  gemm_bt<<<512, 512, 0, stream>>>(x2, w2b, ifeats, b2, out);
}

// Round 5
// 155.012 us; speedup vs baseline: 1.0891x; 1.0192x over previous
//
#include <hip/hip_runtime.h>
#include <cstdint>

#define DIMD 1024
#define NROWS 8192
#define KDIM 2048   // 2*DIM

typedef unsigned short u16;
typedef __bf16 bf16x8 __attribute__((ext_vector_type(8)));
typedef float f32x4 __attribute__((ext_vector_type(4)));

__device__ __forceinline__ u16 f2bf(float f) {
  unsigned u = __builtin_bit_cast(unsigned, f);
  return (u16)((u + 0x7FFFu + ((u >> 16) & 1u)) >> 16);  // RNE
}

// Branch-free exact-enough GELU (A&S 7.1.26 erf, |err| <= 1.5e-7).
__device__ __forceinline__ float gelu_exact(float x) {
  float s = 0.70710678118654752f * x;
  float a = fabsf(s);
  float k = __fdividef(1.0f, fmaf(0.3275911f, a, 1.0f));
  float p = 1.061405429f;
  p = fmaf(p, k, -1.453152027f);
  p = fmaf(p, k, 1.421413741f);
  p = fmaf(p, k, -0.284496736f);
  p = fmaf(p, k, 0.254829592f);
  p = p * k;
  float e = __expf(-s * s);
  float erf_s = copysignf(fmaf(-p, e, 1.0f), s);
  return 0.5f * x * (1.0f + erf_s);
}

// ---------------------------------------------------------------------------
// pre_kernel v2 (unchanged from r4): conv(3x5)+bias+gelu -> x2 bf16, w2 cast.
// ---------------------------------------------------------------------------
__global__ __launch_bounds__(256) void pre_kernel(
    const float* __restrict__ ifeats, const float* __restrict__ tn,
    const float* __restrict__ ta, const float* __restrict__ cw,
    const float* __restrict__ cb, const float* __restrict__ w2,
    u16* __restrict__ x2, u16* __restrict__ w2b) {
  const int b = blockIdx.x;
  const int t = threadIdx.x;
  if (b < 1024) {                  // 8 rows per block
    const int c = t >> 7;          // out channel 0/1
    const int w0 = (t & 127) << 3; // 8 outputs starting here
    float cwn[5], cwa[5], cwi[5];
#pragma unroll
    for (int k = 0; k < 5; ++k) {
      cwn[k] = cw[c * 15 + k];
      cwa[k] = cw[c * 15 + 5 + k];
      cwi[k] = cw[c * 15 + 10 + k];
    }
    const float bias = cb[c];
    // Row-invariant part: base[s] = bias + conv5(tn) + conv5(ta).
    float base[8];
    {
      float wn[12], wa[12];
#pragma unroll
      for (int j = 0; j < 12; ++j) {
        int wp = w0 - 2 + j;
        bool ok = (wp >= 0) && (wp < DIMD);
        wn[j] = ok ? tn[ok ? wp : 0] : 0.f;
        wa[j] = ok ? ta[ok ? wp : 0] : 0.f;
      }
#pragma unroll
      for (int s = 0; s < 8; ++s) {
        float x = bias;
#pragma unroll
        for (int k = 0; k < 5; ++k) {
          x = fmaf(cwn[k], wn[s + k], x);
          x = fmaf(cwa[k], wa[s + k], x);
        }
        base[s] = x;
      }
    }
    const bool has_l = (w0 > 0);
    const bool has_r = (w0 < DIMD - 8);
#pragma unroll 1
    for (int r = 0; r < 8; ++r) {
      const int row = b * 8 + r;
      const float* irow = ifeats + (size_t)row * DIMD;
      float wi[12];
      float4 m0 = *(const float4*)(irow + w0);
      float4 m1 = *(const float4*)(irow + w0 + 4);
      wi[0] = has_l ? irow[w0 - 2] : 0.f;
      wi[1] = has_l ? irow[w0 - 1] : 0.f;
      wi[2] = m0.x; wi[3] = m0.y; wi[4] = m0.z; wi[5] = m0.w;
      wi[6] = m1.x; wi[7] = m1.y; wi[8] = m1.z; wi[9] = m1.w;
      wi[10] = has_r ? irow[w0 + 8] : 0.f;
      wi[11] = has_r ? irow[w0 + 9] : 0.f;
      union { u16 o[8]; uint4 u; } pk;
#pragma unroll
      for (int s = 0; s < 8; ++s) {
        float x = base[s];
#pragma unroll
        for (int k = 0; k < 5; ++k) x = fmaf(cwi[k], wi[s + k], x);
        pk.o[s] = f2bf(gelu_exact(x));
      }
      *(uint4*)(x2 + (size_t)row * KDIM + c * DIMD + w0) = pk.u;
    }
  } else {
    const int t2 = (b - 1024) * 256 + t;
    const float4* p = (const float4*)(w2 + (size_t)t2 * 8);
    float4 a = p[0], bb = p[1];
    union { u16 o[8]; uint4 v; } pk;
    pk.o[0] = f2bf(a.x);  pk.o[1] = f2bf(a.y);  pk.o[2] = f2bf(a.z);  pk.o[3] = f2bf(a.w);
    pk.o[4] = f2bf(bb.x); pk.o[5] = f2bf(bb.y); pk.o[6] = f2bf(bb.z); pk.o[7] = f2bf(bb.w);
    *(uint4*)(w2b + (size_t)t2 * 8) = pk.v;
  }
}

// ---------------------------------------------------------------------------
// GEMM v6: m201-style phase pipeline at BM=256, BN=128, BK=64.
//   8 waves (512 thr), per-wave 64x64 (4x4 acc): frag reads drop to 16
//   b128/wave/K-tile (r0: 24) -> per-CU LDS demand ~1920 cyc/K-tile (r0:
//   ~2800, which was 77% of its 48.6 us => LDS-pipe-bound).
//   Grid 256 blocks = 1/CU; latency hidden IN-block by the counted pipeline
//   (r3's 1-block/CU failed because its 2-phase structure exposed full
//   drains; m201 runs 1 block/CU at 62% MfmaUtil).
//   3-deep LDS rotation (144 KB); tile t+2 issued during iter t (A-part in
//   phase A, B-part in phase B), drained end of iter t+1 via vmcnt(6)
//   (6 loads/thread/tile; never 0 in steady state) -> 2-iter flight ~1400
//   cyc > 900-cyc HBM miss latency.
//   Phases: 16 MFMA each, setprio(1) wrapped, s_barrier before each MFMA
//   cluster (m201 placement), sched_barrier(0) after barriers.
//   XOR chunk swizzle kept verbatim (verified 0 conflicts r0-r4).
// ---------------------------------------------------------------------------
__device__ __forceinline__ void gl_lds16(const u16* g, u16* l) {
  __builtin_amdgcn_global_load_lds(
      (__attribute__((address_space(1))) void*)g,
      (__attribute__((address_space(3))) void*)l, 16, 0, 0);
}

#define BK 64       // u16 per row per K-tile
#define BM 256
#define BN 128
#define NTILE 32    // KDIM / BK

__global__ __launch_bounds__(512, 1) void gemm_bt(
    const u16* __restrict__ A,      // x2 bf16 [8192, 2048]
    const u16* __restrict__ B,      // w2 bf16 [1024, 2048]
    const float* __restrict__ ifeats,
    const float* __restrict__ b2,
    float* __restrict__ out) {
  constexpr int K = KDIM;
  __shared__ __align__(16) u16 sA[3][BM * BK];  // 3 x 32 KB
  __shared__ __align__(16) u16 sB[3][BN * BK];  // 3 x 16 KB; 144 KB total

  const int tid = threadIdx.x;
  const int wv = tid >> 6;         // wave 0..7
  const int lane = tid & 63;
  // XCD swizzle: 256 blocks; xcd = id&7 owns 4 M-strips x 8 N-blocks
  // (A-panels 1MB x4 stay L2-resident per XCD; B fully shared).
  const int id = blockIdx.x;       // 0..255
  const int xcd = id & 7;
  const int s_ = id >> 3;          // 0..31
  const int i0 = (xcd * 4 + (s_ >> 3)) * BM;
  const int j0 = (s_ & 7) * BN;

  const int wm = (wv >> 1) * 64;   // wave tile: 64 (M) x 64 (N); 4M x 2N waves
  const int wn = (wv & 1) * 64;
  const int quad = lane >> 4;
  const int r16 = lane & 15;
  const int sw = r16 & 7;

  // staging: unit = 8 rows x 128 B = one gl_lds16 (wave-uniform LDS base).
  // A: 256 rows = 4 units/wave; B: 128 rows = 2 units/wave. 6 loads/thr/tile.
  const int srow = lane >> 3;                 // 0..7
  const int schunk = (lane & 7) ^ srow;       // XOR-swizzled 16B chunk
  const u16* gA[4];
  const u16* gB[2];
#pragma unroll
  for (int u = 0; u < 4; ++u)
    gA[u] = A + (size_t)(i0 + wv * 32 + u * 8 + srow) * K + schunk * 8;
#pragma unroll
  for (int u = 0; u < 2; ++u)
    gB[u] = B + (size_t)(j0 + wv * 16 + u * 8 + srow) * K + schunk * 8;

  const f32x4 vzero = {0.f, 0.f, 0.f, 0.f};
  f32x4 acc[4][4];
#pragma unroll
  for (int a = 0; a < 4; ++a)
#pragma unroll
    for (int b = 0; b < 4; ++b) acc[a][b] = vzero;

  u16* pa0 = (u16*)sA[0]; u16* pa1 = (u16*)sA[1]; u16* pa2 = (u16*)sA[2];
  u16* pb0 = (u16*)sB[0]; u16* pb1 = (u16*)sB[1]; u16* pb2 = (u16*)sB[2];

  auto issueA = [&](u16* buf, int t) {
#pragma unroll
    for (int u = 0; u < 4; ++u)
      gl_lds16(gA[u] + t * BK, buf + (wv * 32 + u * 8) * BK);
  };
  auto issueB = [&](u16* buf, int t) {
#pragma unroll
    for (int u = 0; u < 2; ++u)
      gl_lds16(gB[u] + t * BK, buf + (wv * 16 + u * 8) * BK);
  };
  auto rdfrag = [&](const u16* buf, int row, int ks) -> bf16x8 {
    return *(const bf16x8*)&buf[(row + r16) * BK + (((ks * 4 + quad) ^ sw) << 3)];
  };

  // Prologue: tile0 -> buf0, tile1 -> buf1; drain tile0 (keep tile1's 6).
  issueA(pa0, 0); issueB(pb0, 0);
  issueA(pa1, 1); issueB(pb1, 1);
  asm volatile("s_waitcnt vmcnt(6)" ::: "memory");
  __builtin_amdgcn_s_barrier();
  __builtin_amdgcn_sched_barrier(0);

  for (int t = 0; t < NTILE; ++t) {
    const bool pf = (t + 2) < NTILE;
    // ---------------- phase A: acc[0..1][0..3] ----------------
    bf16x8 av[2][2], bv[4][2];
#pragma unroll
    for (int mt = 0; mt < 2; ++mt)
#pragma unroll
      for (int ks = 0; ks < 2; ++ks) av[mt][ks] = rdfrag(pa0, wm + mt * 16, ks);
#pragma unroll
    for (int nt = 0; nt < 4; ++nt)
#pragma unroll
      for (int ks = 0; ks < 2; ++ks) bv[nt][ks] = rdfrag(pb0, wn + nt * 16, ks);
    if (pf) issueA(pa2, t + 2);              // tile t+2 A-part into freed buf
    __builtin_amdgcn_s_barrier();
    __builtin_amdgcn_sched_barrier(0);
    __builtin_amdgcn_s_setprio(1);
#pragma unroll
    for (int ks = 0; ks < 2; ++ks)
#pragma unroll
      for (int mt = 0; mt < 2; ++mt)
#pragma unroll
        for (int nt = 0; nt < 4; ++nt)
          acc[mt][nt] = __builtin_amdgcn_mfma_f32_16x16x32_bf16(av[mt][ks], bv[nt][ks], acc[mt][nt], 0, 0, 0);
    __builtin_amdgcn_s_setprio(0);
    // ---------------- phase B: acc[2..3][0..3] ----------------
    bf16x8 aw[2][2];
#pragma unroll
    for (int mt = 0; mt < 2; ++mt)
#pragma unroll
      for (int ks = 0; ks < 2; ++ks) aw[mt][ks] = rdfrag(pa0, wm + (mt + 2) * 16, ks);
    if (pf) issueB(pb2, t + 2);              // tile t+2 B-part
    __builtin_amdgcn_s_barrier();
    __builtin_amdgcn_sched_barrier(0);
    __builtin_amdgcn_s_setprio(1);
#pragma unroll
    for (int ks = 0; ks < 2; ++ks)
#pragma unroll
      for (int mt = 0; mt < 2; ++mt)
#pragma unroll
        for (int nt = 0; nt < 4; ++nt)
          acc[mt + 2][nt] = __builtin_amdgcn_mfma_f32_16x16x32_bf16(aw[mt][ks], bv[nt][ks], acc[mt + 2][nt], 0, 0, 0);
    __builtin_amdgcn_s_setprio(0);
    // Counted drain: tile t+1 must be resident for iter t+1; keep t+2's 6
    // loads in flight. Tail: drain all.
    if (pf) asm volatile("s_waitcnt vmcnt(6)" ::: "memory");
    else    asm volatile("s_waitcnt vmcnt(0)" ::: "memory");
    __builtin_amdgcn_s_barrier();
    __builtin_amdgcn_sched_barrier(0);
    // rotate 3-deep buffers
    u16* x;
    x = pa0; pa0 = pa1; pa1 = pa2; pa2 = x;
    x = pb0; pb0 = pb1; pb1 = pb2; pb2 = x;
  }

  // epilogue: C/D layout col=lane&15, row=quad*4+reg
#pragma unroll
  for (int nt = 0; nt < 4; ++nt) {
    int col = j0 + wn + nt * 16 + r16;
    float bias = b2[col];
#pragma unroll
    for (int mt = 0; mt < 4; ++mt) {
      int rbase = i0 + wm + mt * 16 + quad * 4;
#pragma unroll
      for (int r = 0; r < 4; ++r) {
        size_t idx = (size_t)(rbase + r) * DIMD + col;
        out[idx] = ifeats[idx] + bias + acc[mt][nt][r];
      }
    }
  }
}

// ---------------------------------------------------------------------------
extern "C" void kernel_launch(void* const* d_in, const int* in_sizes, int n_in,
                              void* d_out, int out_size, void* d_ws, size_t ws_size,
                              hipStream_t stream) {
  const float* ifeats = (const float*)d_in[0];
  const float* tn     = (const float*)d_in[1];
  const float* ta     = (const float*)d_in[2];
  const float* cw     = (const float*)d_in[3];
  const float* cb     = (const float*)d_in[4];
  const float* w2     = (const float*)d_in[5];
  const float* b2     = (const float*)d_in[6];
  float* out = (float*)d_out;

  // ws: [0, 4MB) w2 bf16 | [4MB, 36MB) x2 bf16
  u16* w2b = (u16*)d_ws;
  u16* x2  = (u16*)((char*)d_ws + (size_t)DIMD * KDIM * 2);

  pre_kernel<<<2048, 256, 0, stream>>>(ifeats, tn, ta, cw, cb, w2, x2, w2b);
  gemm_bt<<<256, 512, 0, stream>>>(x2, w2b, ifeats, b2, out);
}